// Round 4
// baseline (376.219 us; speedup 1.0000x reference)
//
#include <hip/hip_runtime.h>
#include <math.h>

#define N_CH 17
#define HW 128
#define EDGE (32.f / 28.f)

#define W0 (1.f/32.f)
#define W1 (3.f/32.f)
#define W2 (5.f/32.f)
#define W3 (7.f/32.f)

// float4 component-wise shuffle helpers (wave64)
#define SHFL_UP4(d, s, delta)                                   \
    d.x = __shfl_up(s.x, delta); d.y = __shfl_up(s.y, delta);   \
    d.z = __shfl_up(s.z, delta); d.w = __shfl_up(s.w, delta);
#define SHFL_DN4(d, s, delta)                                       \
    d.x = __shfl_down(s.x, delta); d.y = __shfl_down(s.y, delta);   \
    d.z = __shfl_down(s.z, delta); d.w = __shfl_down(s.w, delta);

// 8-tap (1,3,5,7,7,5,3,1)/32 on one component C of eight float4 rows
#define TAPC(d, a0,a1,a2,a3,a4,a5,a6,a7, C)                              \
    d.C = W0*a0.C + W1*a1.C + W2*a2.C + W3*a3.C                          \
        + W3*a4.C + W2*a5.C + W1*a6.C + W0*a7.C;
#define TAP4(d, a0,a1,a2,a3,a4,a5,a6,a7)         \
    TAPC(d, a0,a1,a2,a3,a4,a5,a6,a7, x)          \
    TAPC(d, a0,a1,a2,a3,a4,a5,a6,a7, y)          \
    TAPC(d, a0,a1,a2,a3,a4,a5,a6,a7, z)          \
    TAPC(d, a0,a1,a2,a3,a4,a5,a6,a7, w)

__global__ __launch_bounds__(256, 4)
void heatmap_kernel(const float* __restrict__ x,
                    float* __restrict__ out_heat,   // [N,3,16,8]
                    float* __restrict__ out_mr,     // [N,3]
                    float* __restrict__ out_mi) {   // [N,17,2]
    const int n = blockIdx.x;
    const int t = threadIdx.x;
    const int w = t >> 6, l = t & 63;
    const int g  = l >> 3;   // row-group: lane owns input rows 8g..8g+7
    const int cq = l & 7;    // col-quad:  lane owns input cols 4cq..4cq+3

    __shared__ float s_part[12 * HW];   // [4 waves][3 groups][128] = 6 KB
    __shared__ float s_cval[N_CH];

    const float* xn = x + (size_t)n * N_CH * 2048;
    // float4 index of (row 8g, cols 4cq..4cq+3); row k adds 8
    const int fbase = g * 64 + cq;

    // output positions owned by this lane (row-major 16x8 flat index)
    const int p0 = g * 16 + cq;   // row 2g,   col cq
    const int p1 = p0 + 8;        // row 2g+1, col cq
    const float cs2 = (cq == 0 || cq == 7) ? EDGE : 1.f;

    // per-wave group accumulators for positions p0 (lo) / p1 (hi)
    float ga0l = 0.f, ga0h = 0.f, ga1l = 0.f, ga1h = 0.f, ga2l = 0.f, ga2h = 0.f;

    // current channel: 8 consecutive rows (float4 of 4 cols each), in registers
    float4 v0, v1, v2, v3, v4, v5, v6, v7;
    {
        const float4* src = (const float4*)(xn + (size_t)w * 2048);
        v0 = src[fbase];      v1 = src[fbase + 8];  v2 = src[fbase + 16]; v3 = src[fbase + 24];
        v4 = src[fbase + 32]; v5 = src[fbase + 40]; v6 = src[fbase + 48]; v7 = src[fbase + 56];
    }

#pragma unroll
    for (int i = 0; i < 5; ++i) {
        const int c = w + 4 * i;          // wave-uniform channel
        if (c >= N_CH) break;             // wave 0 runs 5 iters, others 4

        // prefetch this wave's next channel; flies during the register compute
        float4 n0, n1, n2, n3, n4, n5, n6, n7;
        const bool more = (c + 4 < N_CH);
        if (more) {
            const float4* src = (const float4*)(xn + (size_t)(c + 4) * 2048);
            n0 = src[fbase];      n1 = src[fbase + 8];  n2 = src[fbase + 16]; n3 = src[fbase + 24];
            n4 = src[fbase + 32]; n5 = src[fbase + 40]; n6 = src[fbase + 48]; n7 = src[fbase + 56];
        }

        // ---- stage 1 (H 64->16), all in registers ----
        // rows 8g-2, 8g-1 live in lane l-8 (its v6,v7); rows 8g+8,8g+9 in lane l+8 (v0,v1)
        float4 um2, um1, dp0, dp1;
        SHFL_UP4(um2, v6, 8)
        SHFL_UP4(um1, v7, 8)
        SHFL_DN4(dp0, v0, 8)
        SHFL_DN4(dp1, v1, 8)
        if (g == 0) { um2.x=um2.y=um2.z=um2.w=0.f; um1.x=um1.y=um1.z=um1.w=0.f; }
        if (g == 7) { dp0.x=dp0.y=dp0.z=dp0.w=0.f; dp1.x=dp1.y=dp1.z=dp1.w=0.f; }

        float4 r0, r1;   // output rows 2g and 2g+1 (4 cols each)
        TAP4(r0, um2, um1, v0, v1, v2, v3, v4, v5)       // rows 8g-2..8g+5
        TAP4(r1, v2, v3, v4, v5, v6, v7, dp0, dp1)       // rows 8g+2..8g+9
        if (g == 0) { r0.x *= EDGE; r0.y *= EDGE; r0.z *= EDGE; r0.w *= EDGE; }
        if (g == 7) { r1.x *= EDGE; r1.y *= EDGE; r1.z *= EDGE; r1.w *= EDGE; }

        // ---- stage 2 (W 32->8): need cols 4cq-2..4cq+5 ----
        float lm2 = __shfl_up(r0.z, 1), lm1 = __shfl_up(r0.w, 1);
        float rp0 = __shfl_down(r0.x, 1), rp1 = __shfl_down(r0.y, 1);
        if (cq == 0) { lm2 = 0.f; lm1 = 0.f; }
        if (cq == 7) { rp0 = 0.f; rp1 = 0.f; }
        float olo = (W0*lm2 + W1*lm1 + W2*r0.x + W3*r0.y
                   + W3*r0.z + W2*r0.w + W1*rp0 + W0*rp1) * cs2;

        float lh2 = __shfl_up(r1.z, 1), lh1 = __shfl_up(r1.w, 1);
        float rh0 = __shfl_down(r1.x, 1), rh1 = __shfl_down(r1.y, 1);
        if (cq == 0) { lh2 = 0.f; lh1 = 0.f; }
        if (cq == 7) { rh0 = 0.f; rh1 = 0.f; }
        float ohi = (W0*lh2 + W1*lh1 + W2*r1.x + W3*r1.y
                   + W3*r1.z + W2*r1.w + W1*rh0 + W0*rh1) * cs2;

        // group accumulation (c wave-uniform -> scalar branch)
        if (c < 5)       { ga0l += olo; ga0h += ohi; }
        else if (c < 11) { ga1l += olo; ga1h += ohi; }
        else             { ga2l += olo; ga2h += ohi; }

        // per-channel max/argmax over 128 positions (first-index tiebreak; p0 < p1)
        {
            float bv; int bi;
            if (ohi > olo) { bv = ohi; bi = p1; } else { bv = olo; bi = p0; }
#pragma unroll
            for (int off = 32; off >= 1; off >>= 1) {
                float ov = __shfl_down(bv, off);
                int   oi = __shfl_down(bi, off);
                if (ov > bv || (ov == bv && oi < bi)) { bv = ov; bi = oi; }
            }
            if (l == 0) {
                s_cval[c] = bv;
                float* mi = out_mi + ((size_t)n * N_CH + c) * 2;
                mi[0] = (float)(bi & 7);
                mi[1] = (float)(bi >> 3);
            }
        }

        if (more) { v0=n0; v1=n1; v2=n2; v3=n3; v4=n4; v5=n5; v6=n6; v7=n7; }
    }

    // cross-wave combine (only block-wide sync in the kernel)
    s_part[(w * 3 + 0) * HW + p0] = ga0l;
    s_part[(w * 3 + 0) * HW + p1] = ga0h;
    s_part[(w * 3 + 1) * HW + p0] = ga1l;
    s_part[(w * 3 + 1) * HW + p1] = ga1h;
    s_part[(w * 3 + 2) * HW + p0] = ga2l;
    s_part[(w * 3 + 2) * HW + p1] = ga2h;
    __syncthreads();

    if (w < 3) {
        const int grp = w;   // softmax over the 128 positions of group grp
        float lo = s_part[(0 * 3 + grp) * HW + l]      + s_part[(1 * 3 + grp) * HW + l]
                 + s_part[(2 * 3 + grp) * HW + l]      + s_part[(3 * 3 + grp) * HW + l];
        float hi = s_part[(0 * 3 + grp) * HW + l + 64] + s_part[(1 * 3 + grp) * HW + l + 64]
                 + s_part[(2 * 3 + grp) * HW + l + 64] + s_part[(3 * 3 + grp) * HW + l + 64];
        float m = fmaxf(lo, hi);
#pragma unroll
        for (int off = 1; off < 64; off <<= 1) m = fmaxf(m, __shfl_xor(m, off));
        float e0 = expf(lo - m), e1 = expf(hi - m);
        float s = e0 + e1;
#pragma unroll
        for (int off = 1; off < 64; off <<= 1) s += __shfl_xor(s, off);
        float inv = 1.f / s;
        float* dsto = out_heat + ((size_t)n * 3 + grp) * HW;
        dsto[l]      = e0 * inv;
        dsto[l + 64] = e1 * inv;
    } else if (l < 3) {
        // wave 3: group means of per-channel maxes
        int lo = (l == 0) ? 0 : ((l == 1) ? 5 : 11);
        int hi = (l == 0) ? 5 : ((l == 1) ? 11 : 17);
        float acc = 0.f;
        for (int c2 = lo; c2 < hi; ++c2) acc += s_cval[c2];
        out_mr[(size_t)n * 3 + l] = acc / (float)(hi - lo);
    }
}

extern "C" void kernel_launch(void* const* d_in, const int* in_sizes, int n_in,
                              void* d_out, int out_size, void* d_ws, size_t ws_size,
                              hipStream_t stream) {
    const float* x = (const float*)d_in[0];
    float* out = (float*)d_out;
    const int N = in_sizes[0] / (N_CH * 64 * 32);      // 2048
    float* out_heat = out;                             // N*3*128
    float* out_mr   = out_heat + (size_t)N * 3 * HW;   // N*3
    float* out_mi   = out_mr + (size_t)N * 3;          // N*17*2
    heatmap_kernel<<<dim3(N), dim3(256), 0, stream>>>(x, out_heat, out_mr, out_mi);
}